// Round 3
// baseline (142605.737 us; speedup 1.0000x reference)
//
#include <hip/hip_runtime.h>

#define HH    100
#define G4    400
#define LSEQ  168
#define STEPS 48
#define NTICK 8066     // L0 at tick t (t<8064), L1 at tick t-1
#define SHP   112      // padded h stride (zeros beyond 100)
#define NX    176      // extra rows: Wih1 368..399 (32) + Whh1 256..399 (144)
#define NX4   4400     // float4 units in the extra-row panel
#define NX4P  4416     // padded (waves 13..15 read up to idx 4415)

__device__ __forceinline__ float sigmoidf_(float x) {
    return 1.0f / (1.0f + __expf(-x));
}
__device__ __forceinline__ float tanhf_(float x) {
    return 1.0f - 2.0f / (__expf(2.0f * x) + 1.0f);
}
// readlane: broadcast lane l's value into an SGPR (consumed as FMA scalar src)
__device__ __forceinline__ float rl_(float v, int l) {
    return __uint_as_float(__builtin_amdgcn_readlane(__float_as_uint(v), l));
}

// Extra-row weights packed transposed for coalesced dwordx4 access.
// float4 units:
//   group 0 (wave 4, B-extras):  idx4 = c*32 + l           row = 368+l (l<32), src Wih1
//   group g=1..3 (waves 13..15): idx4 = 800 + (g-1)*1200 + c*48 + l
//                                row = 256 + (g-1)*48 + l (l<48), src Whh1
// c = 0..24 chunks of 4 (covers k=0..99 exactly). Total 4400 float4 = 70,400 B.
__global__ void prep_kernel(const float* __restrict__ Wih1,
                            const float* __restrict__ Whh1,
                            float* __restrict__ wsT) {
    int idx = blockIdx.x * 256 + threadIdx.x;     // float index
    if (idx >= NX4 * 4) return;
    int f = idx & 3, q4 = idx >> 2;
    float v;
    if (q4 < 800) {
        int c = q4 / 32, l = q4 % 32;
        v = Wih1[(368 + l) * HH + c * 4 + f];
    } else {
        int r = q4 - 800, grp = r / 1200, rr = r % 1200;
        int c = rr / 48, l = rr % 48;
        v = Whh1[(256 + grp * 48 + l) * HH + c * 4 + f];
    }
    wsT[idx] = v;
}

// 1024 threads = 16 waves = 4 waves/SIMD -> HARD 128-VGPR cap (16 waves must
// co-reside for the single WG; >128 VGPRs would make the WG unlaunchable).
// Wave-aligned unit map (thread t owns one K=100 row-unit):
//   t <  400 : Whh0 row t        (input h0)  -> L0 gate partial, gAll[b][t]
//   t <  768 : Wih1 row t-400    (input h0)  -> L1 "a" partial,  gAll[b][400+r]
//   t < 1024 : Whh1 row t-768    (input h1)  -> L1 "b" partial,  gAll[b][768+r]
// Extra rows staged in LDS (xlds), one heavy wave per SIMD:
//   wave  4 : Wih1 rows 368..399 (h0) -> gX[b][144+l]
//   wave 13 : Whh1 rows 256..303 (h1) -> gX[b][l]
//   wave 14 : Whh1 rows 304..351 (h1) -> gX[b][48+l]
//   wave 15 : Whh1 rows 352..399 (h1) -> gX[b][96+l]
// h distribution: ONE ds_read_b128/wave (lane c holds h-chunk c for both
// batches of the wave's input layer), then v_readlane -> SGPR -> FMA scalar.
// sched_barrier(0) per unrolled iteration: the 200 readlanes depend only on
// the loop-invariant hv, so without a fence the scheduler clusters them,
// overflows the SGPR file, cascades into VGPR scratch spill (rounds 1/2:
// ~26 floats/thread/tick reloaded from HBM = 214 GB FETCH, 3x slower than
// the pre-readlane baseline). The fence caps live readlane results at ~8.
__global__
__attribute__((amdgpu_flat_work_group_size(1024, 1024), amdgpu_waves_per_eu(4, 4)))
void lstm_kernel(const float* __restrict__ X,     // (512,168)
                 const float* __restrict__ Wih0,  // (400,1)
                 const float* __restrict__ Whh0,  // (400,100)
                 const float* __restrict__ bih0,
                 const float* __restrict__ bhh0,
                 const float* __restrict__ Wih1,  // (400,100)
                 const float* __restrict__ Whh1,  // (400,100)
                 const float* __restrict__ bih1,
                 const float* __restrict__ bhh1,
                 const float* __restrict__ fcw,   // (100)
                 const float* __restrict__ fcb,   // (1)
                 const float* __restrict__ wsT,   // extra rows, packed
                 float* __restrict__ out)         // (512,48)
{
    __shared__ __align__(16) float shs[2][2][SHP];   // [layer][batch][k], pad zeros
    __shared__ __align__(16) float4 wlds[2][1024];   // weight chunks 23,24 per unit
    __shared__ __align__(16) float4 xlds[NX4P];      // extra-row panel (70.6 KB)
    __shared__ float gAll[2][1024];                  // per-batch unit partials
    __shared__ float gX[2][NX];                      // extra-row full-dot partials
    __shared__ float sb0[G4], sb1[G4], sw0[G4], sfcw[HH];
    __shared__ float yacc[2], ybuf[2];

    const int t    = threadIdx.x;
    const int lane = t & 63;
    const int wid  = t >> 6;
    const int wg   = blockIdx.x;
    const int b0   = wg * 2;

    // ---- one-time init ----
    for (int i = t; i < 2 * 2 * SHP; i += 1024) ((float*)shs)[i] = 0.0f;
    for (int i = t; i < NX4P; i += 1024)
        xlds[i] = (i < NX4) ? ((const float4*)wsT)[i] : make_float4(0.f, 0.f, 0.f, 0.f);
    if (t < G4) {
        sb0[t] = bih0[t] + bhh0[t];
        sb1[t] = bih1[t] + bhh1[t];
        sw0[t] = Wih0[t];
    }
    if (t < HH) sfcw[t] = fcw[t];
    if (t == 0) { yacc[0] = yacc[1] = 0.0f; ybuf[0] = ybuf[1] = 0.0f; }
    const float fcb0 = fcb[0];

    // ---- register-resident weights: 92 floats (23 float4 chunks) ----
    const float* wrow = (t < 400) ? (Whh0 + t * HH)
                      : (t < 768) ? (Wih1 + (t - 400) * HH)
                                  : (Whh1 + (t - 768) * HH);
    float wv[92];
    #pragma unroll
    for (int j = 0; j < 23; ++j) {
        float4 a = ((const float4*)wrow)[j];
        wv[4*j] = a.x; wv[4*j+1] = a.y; wv[4*j+2] = a.z; wv[4*j+3] = a.w;
    }
    // Pin in VGPRs: opaque asm outputs cannot be rematerialized as reloads.
    #pragma unroll
    for (int j = 0; j < 92; j += 4)
        asm volatile("" : "+v"(wv[j]), "+v"(wv[j+1]), "+v"(wv[j+2]), "+v"(wv[j+3]));
    // chunks 23,24 live in LDS
    wlds[0][t] = ((const float4*)wrow)[23];
    wlds[1][t] = ((const float4*)wrow)[24];

    // wave-uniform input layer for the main FMA (h0 for waves 0..11, h1 for 12..15)
    const float* hbase = (t < 768) ? &shs[0][0][0] : &shs[1][0][0];

    // extra-row stream config (wave-uniform)
    const bool xtr   = (wid == 4) || (wid >= 13);
    const int  nact  = (wid == 4) ? 32 : 48;
    const int  xbase = (wid == 4) ? 0 : 800 + (wid - 13) * 1200;
    const int  xu0   = (wid == 4) ? 144 : (wid - 13) * 48;
    const float4* xw = xlds + xbase + lane;          // + c*nact per chunk (LDS)

    // cell-update params
    float c0 = 0.0f, c1 = 0.0f;
    const int ub = (t < 200) ? (t / 100) : ((t - 200) / 100);
    const int uj = (t < 200) ? (t % 100) : ((t - 200) % 100);
    const float* xrow = X + (b0 + ub) * LSEQ;

    __syncthreads();

    #pragma unroll 1
    for (int tick = 0; tick < NTICK; ++tick) {
        const bool ydtick = (tick >= 2) && ((tick - 2) % LSEQ == LSEQ - 1);

        // ================= Phase A: all FMA work =================
        {
            // lane c holds h chunk c: batch A = chunks 0..24, batch B = 28..52
            const int li = (lane < 56) ? lane : 55;
            const float4 hv = ((const float4*)hbase)[li];   // ONE ds_read_b128
            float a0 = 0.f, a1 = 0.f, xa0 = 0.f, xa1 = 0.f;

#define PHASE_A_LOOP(DO_X)                                                     \
            _Pragma("unroll")                                                  \
            for (int c = 0; c < 25; ++c) {                                     \
                const float sA0 = rl_(hv.x, c),      sA1 = rl_(hv.y, c);       \
                const float sA2 = rl_(hv.z, c),      sA3 = rl_(hv.w, c);       \
                const float sB0 = rl_(hv.x, 28 + c), sB1 = rl_(hv.y, 28 + c);  \
                const float sB2 = rl_(hv.z, 28 + c), sB3 = rl_(hv.w, 28 + c);  \
                float w0, w1, w2, w3;                                          \
                if (c < 23) {                                                  \
                    w0 = wv[4*c]; w1 = wv[4*c+1]; w2 = wv[4*c+2]; w3 = wv[4*c+3]; \
                } else {                                                       \
                    float4 wl = wlds[c - 23][t];                               \
                    w0 = wl.x; w1 = wl.y; w2 = wl.z; w3 = wl.w;                \
                }                                                              \
                a0 += w0*sA0 + w1*sA1 + w2*sA2 + w3*sA3;                       \
                a1 += w0*sB0 + w1*sB1 + w2*sB2 + w3*sB3;                       \
                if (DO_X) {                                                    \
                    const float4 w4 = xw[c * nact];                            \
                    xa0 += w4.x*sA0 + w4.y*sA1 + w4.z*sA2 + w4.w*sA3;          \
                    xa1 += w4.x*sB0 + w4.y*sB1 + w4.z*sB2 + w4.w*sB3;          \
                }                                                              \
                __builtin_amdgcn_sched_barrier(0);                             \
            }

            if (xtr) { PHASE_A_LOOP(true) } else { PHASE_A_LOOP(false) }
#undef PHASE_A_LOOP

            gAll[0][t] = a0; gAll[1][t] = a1;
            if (xtr && lane < nact) { gX[0][xu0 + lane] = xa0; gX[1][xu0 + lane] = xa1; }
        }
        if (ydtick && t < 200) {
            atomicAdd(&yacc[ub], sfcw[uj] * shs[1][ub][uj]);
        }
        __syncthreads();

        // ================= Phase B: cell updates =================
        if (t < 200) {
            if (tick < 8064) {               // L0, global step g0 = tick
                const int s = tick / LSEQ, p = tick % LSEQ;
                float x;
                if (s == 0)            x = xrow[p];
                else if (p < LSEQ - 1) x = xrow[p + 1];
                else                   x = ybuf[ub];
                const int j = uj, b = ub;
                float Gi = sb0[j]       + sw0[j]       * x + gAll[b][j];
                float Gf = sb0[100 + j] + sw0[100 + j] * x + gAll[b][100 + j];
                float Gg = sb0[200 + j] + sw0[200 + j] * x + gAll[b][200 + j];
                float Go = sb0[300 + j] + sw0[300 + j] * x + gAll[b][300 + j];
                c0 = sigmoidf_(Gf) * c0 + sigmoidf_(Gi) * tanhf_(Gg);
                shs[0][b][j] = sigmoidf_(Go) * tanhf_(c0);
            }
        } else if (t < 400) {
            if (tick >= 1 && tick <= 8064) { // L1, global step g1 = tick-1
                const int j = uj, b = ub;
                // Wih1 row r: r<368 -> gAll[b][400+r], else gX[b][144+(r-368)]
                // Whh1 row r: r<256 -> gAll[b][768+r], else gX[b][r-256]
                float Gi = sb1[j]       + gAll[b][400 + j] + gAll[b][768 + j];
                float Gf = sb1[100 + j] + gAll[b][500 + j] + gAll[b][868 + j];
                float Gg = sb1[200 + j] + gAll[b][600 + j]
                         + ((j < 56) ? gAll[b][968 + j] : gX[b][j - 56]);
                float Go = sb1[300 + j]
                         + ((j < 68) ? gAll[b][700 + j] : gX[b][144 + j - 68])
                         + gX[b][44 + j];
                c1 = sigmoidf_(Gf) * c1 + sigmoidf_(Gi) * tanhf_(Gg);
                shs[1][b][j] = sigmoidf_(Go) * tanhf_(c1);
            }
        } else if (t == 1023) {
            if (ydtick) {
                const int s = (tick - 2) / LSEQ;
                float y0 = yacc[0] + fcb0;
                float y1 = yacc[1] + fcb0;
                ybuf[0] = y0; ybuf[1] = y1;
                out[b0 * STEPS + s]       = y0;
                out[(b0 + 1) * STEPS + s] = y1;
                yacc[0] = 0.0f; yacc[1] = 0.0f;
            }
        }
        __syncthreads();
    }
}

extern "C" void kernel_launch(void* const* d_in, const int* in_sizes, int n_in,
                              void* d_out, int out_size, void* d_ws, size_t ws_size,
                              hipStream_t stream) {
    const float* X    = (const float*)d_in[0];
    const float* Wih0 = (const float*)d_in[1];
    const float* Whh0 = (const float*)d_in[2];
    const float* bih0 = (const float*)d_in[3];
    const float* bhh0 = (const float*)d_in[4];
    const float* Wih1 = (const float*)d_in[5];
    const float* Whh1 = (const float*)d_in[6];
    const float* bih1 = (const float*)d_in[7];
    const float* bhh1 = (const float*)d_in[8];
    const float* fcw  = (const float*)d_in[9];
    const float* fcb  = (const float*)d_in[10];
    float* out = (float*)d_out;
    float* wsT = (float*)d_ws;   // 4400 float4 = 70,400 B

    hipLaunchKernelGGL(prep_kernel, dim3((NX4 * 4 + 255) / 256), dim3(256), 0, stream,
                       Wih1, Whh1, wsT);
    hipLaunchKernelGGL(lstm_kernel, dim3(256), dim3(1024), 0, stream,
                       X, Wih0, Whh0, bih0, bhh0, Wih1, Whh1, bih1, bhh1,
                       fcw, fcb, wsT, out);
}

// Round 4
// 120091.895 us; speedup vs baseline: 1.1875x; 1.1875x over previous
//
#include <hip/hip_runtime.h>

#define HH    100
#define G4    400
#define LSEQ  168
#define STEPS 48
#define NTICK 8066     // L0 at tick t (t<8064), L1 at tick t-1
#define SHP   112      // padded h stride (zeros beyond 100)
#define NX    176      // extra rows: Wih1 368..399 (32) + Whh1 256..399 (144)
#define NX4   4400     // float4 units in the extra-row panel
#define NX4P  4416     // padded (waves 13..15 read up to idx 4415)

__device__ __forceinline__ float sigmoidf_(float x) {
    return 1.0f / (1.0f + __expf(-x));
}
__device__ __forceinline__ float tanhf_(float x) {
    return 1.0f - 2.0f / (__expf(2.0f * x) + 1.0f);
}
// readlane: broadcast lane l's value into an SGPR (consumed as FMA scalar src)
__device__ __forceinline__ float rl_(float v, int l) {
    return __uint_as_float(__builtin_amdgcn_readlane(__float_as_uint(v), l));
}

// Extra-row weights packed transposed for coalesced dwordx4 access.
// float4 units:
//   group 0 (wave 4, B-extras):  idx4 = c*32 + l           row = 368+l (l<32), src Wih1
//   group g=1..3 (waves 13..15): idx4 = 800 + (g-1)*1200 + c*48 + l
//                                row = 256 + (g-1)*48 + l (l<48), src Whh1
// c = 0..24 chunks of 4 (covers k=0..99 exactly). Total 4400 float4 = 70,400 B.
__global__ void prep_kernel(const float* __restrict__ Wih1,
                            const float* __restrict__ Whh1,
                            float* __restrict__ wsT) {
    int idx = blockIdx.x * 256 + threadIdx.x;     // float index
    if (idx >= NX4 * 4) return;
    int f = idx & 3, q4 = idx >> 2;
    float v;
    if (q4 < 800) {
        int c = q4 / 32, l = q4 % 32;
        v = Wih1[(368 + l) * HH + c * 4 + f];
    } else {
        int r = q4 - 800, grp = r / 1200, rr = r % 1200;
        int c = rr / 48, l = rr % 48;
        v = Whh1[(256 + grp * 48 + l) * HH + c * 4 + f];
    }
    wsT[idx] = v;
}

// 1024 threads = 16 waves = 4 waves/SIMD -> HARD 128-reg cap (arch VGPR + AGPR,
// gfx950 unified file). Rounds 1-3 lesson: the allocator's arch/acc split is
// heuristic; the readlane loop perturbed it and ~26 of the 92 register weights
// went to scratch instead of AGPRs (-> 220+ GB/dispatch HBM reload = 3x slow).
// Fix: pin 84 weights into AGPRs EXPLICITLY ("a" asm constraint), leaving the
// allocator only ~small arch-VGPR transients. 84 acc + ~40 arch < 128.
//
// Wave-aligned unit map (thread t owns one K=100 row-unit):
//   t <  400 : Whh0 row t        (input h0)  -> L0 gate partial, gAll[b][t]
//   t <  768 : Wih1 row t-400    (input h0)  -> L1 "a" partial,  gAll[b][400+r]
//   t < 1024 : Whh1 row t-768    (input h1)  -> L1 "b" partial,  gAll[b][768+r]
// Extra rows staged in LDS (xlds), one heavy wave per SIMD:
//   wave  4 : Wih1 rows 368..399 (h0) -> gX[b][144+l]
//   wave 13 : Whh1 rows 256..303 (h1) -> gX[b][l]
//   wave 14 : Whh1 rows 304..351 (h1) -> gX[b][48+l]
//   wave 15 : Whh1 rows 352..399 (h1) -> gX[b][96+l]
// h distribution: ONE ds_read_b128/wave (lane c holds h-chunk c for both
// batches of the wave's input layer), then v_readlane -> SGPR -> FMA scalar.
__global__
__attribute__((amdgpu_flat_work_group_size(1024, 1024), amdgpu_waves_per_eu(4, 4)))
void lstm_kernel(const float* __restrict__ X,     // (512,168)
                 const float* __restrict__ Wih0,  // (400,1)
                 const float* __restrict__ Whh0,  // (400,100)
                 const float* __restrict__ bih0,
                 const float* __restrict__ bhh0,
                 const float* __restrict__ Wih1,  // (400,100)
                 const float* __restrict__ Whh1,  // (400,100)
                 const float* __restrict__ bih1,
                 const float* __restrict__ bhh1,
                 const float* __restrict__ fcw,   // (100)
                 const float* __restrict__ fcb,   // (1)
                 const float* __restrict__ wsT,   // extra rows, packed
                 float* __restrict__ out)         // (512,48)
{
    __shared__ __align__(16) float shs[2][2][SHP];   // [layer][batch][k], pad zeros
    __shared__ __align__(16) float4 wlds[4][1024];   // weight chunks 21..24 (64 KB)
    __shared__ __align__(16) float4 xlds[NX4P];      // extra-row panel (70.6 KB)
    __shared__ float gAll[2][1024];                  // per-batch unit partials
    __shared__ float gX[2][NX];                      // extra-row full-dot partials
    __shared__ float sb0[G4], sb1[G4], sw0[G4], sfcw[HH];
    __shared__ float yacc[2], ybuf[2];

    const int t    = threadIdx.x;
    const int lane = t & 63;
    const int wid  = t >> 6;
    const int wg   = blockIdx.x;
    const int b0   = wg * 2;

    // ---- one-time init ----
    for (int i = t; i < 2 * 2 * SHP; i += 1024) ((float*)shs)[i] = 0.0f;
    for (int i = t; i < NX4P; i += 1024)
        xlds[i] = (i < NX4) ? ((const float4*)wsT)[i] : make_float4(0.f, 0.f, 0.f, 0.f);
    if (t < G4) {
        sb0[t] = bih0[t] + bhh0[t];
        sb1[t] = bih1[t] + bhh1[t];
        sw0[t] = Wih0[t];
    }
    if (t < HH) sfcw[t] = fcw[t];
    if (t == 0) { yacc[0] = yacc[1] = 0.0f; ybuf[0] = ybuf[1] = 0.0f; }
    const float fcb0 = fcb[0];

    // ---- persistent weights: chunks 0..20 (84 floats) pinned in AGPRs ----
    const float* wrow = (t < 400) ? (Whh0 + t * HH)
                      : (t < 768) ? (Wih1 + (t - 400) * HH)
                                  : (Whh1 + (t - 768) * HH);
    float wa[84];   // AGPR-resident via "a" constraints (SROA'd to scalars)
    #pragma unroll
    for (int j = 0; j < 21; ++j) {
        float4 a = ((const float4*)wrow)[j];
        asm volatile("v_accvgpr_write_b32 %0, %1" : "=a"(wa[4*j+0]) : "v"(a.x));
        asm volatile("v_accvgpr_write_b32 %0, %1" : "=a"(wa[4*j+1]) : "v"(a.y));
        asm volatile("v_accvgpr_write_b32 %0, %1" : "=a"(wa[4*j+2]) : "v"(a.z));
        asm volatile("v_accvgpr_write_b32 %0, %1" : "=a"(wa[4*j+3]) : "v"(a.w));
    }
    // chunks 21..24 live in LDS
    wlds[0][t] = ((const float4*)wrow)[21];
    wlds[1][t] = ((const float4*)wrow)[22];
    wlds[2][t] = ((const float4*)wrow)[23];
    wlds[3][t] = ((const float4*)wrow)[24];

    // wave-uniform input layer for the main FMA (h0 for waves 0..11, h1 for 12..15)
    const float* hbase = (t < 768) ? &shs[0][0][0] : &shs[1][0][0];

    // extra-row stream config (wave-uniform)
    const bool xtr   = (wid == 4) || (wid >= 13);
    const int  nact  = (wid == 4) ? 32 : 48;
    const int  xbase = (wid == 4) ? 0 : 800 + (wid - 13) * 1200;
    const int  xu0   = (wid == 4) ? 144 : (wid - 13) * 48;
    const float4* xw = xlds + xbase + lane;          // + c*nact per chunk (LDS)

    // cell-update params
    float c0 = 0.0f, c1 = 0.0f;
    const int ub = (t < 200) ? (t / 100) : ((t - 200) / 100);
    const int uj = (t < 200) ? (t % 100) : ((t - 200) % 100);
    const float* xrow = X + (b0 + ub) * LSEQ;

    __syncthreads();

    #pragma unroll 1
    for (int tick = 0; tick < NTICK; ++tick) {
        const bool ydtick = (tick >= 2) && ((tick - 2) % LSEQ == LSEQ - 1);

        // ================= Phase A: all FMA work =================
        {
            // lane c holds h chunk c: batch A = chunks 0..24, batch B = 28..52
            const int li = (lane < 56) ? lane : 55;
            const float4 hv = ((const float4*)hbase)[li];   // ONE ds_read_b128
            float a0 = 0.f, a1 = 0.f, xa0 = 0.f, xa1 = 0.f;

#define PHASE_A_LOOP(DO_X)                                                     \
            _Pragma("unroll")                                                  \
            for (int c = 0; c < 25; ++c) {                                     \
                const float sA0 = rl_(hv.x, c),      sA1 = rl_(hv.y, c);       \
                const float sA2 = rl_(hv.z, c),      sA3 = rl_(hv.w, c);       \
                const float sB0 = rl_(hv.x, 28 + c), sB1 = rl_(hv.y, 28 + c);  \
                const float sB2 = rl_(hv.z, 28 + c), sB3 = rl_(hv.w, 28 + c);  \
                float w0, w1, w2, w3;                                          \
                if (c < 21) {                                                  \
                    /* volatile: must NOT be LICM-hoisted out of the tick   */ \
                    /* loop (84 hoisted reads = arch-VGPR blowup = spill).  */ \
                    asm volatile("v_accvgpr_read_b32 %0, %1"                   \
                                 : "=v"(w0) : "a"(wa[4*c+0]));                 \
                    asm volatile("v_accvgpr_read_b32 %0, %1"                   \
                                 : "=v"(w1) : "a"(wa[4*c+1]));                 \
                    asm volatile("v_accvgpr_read_b32 %0, %1"                   \
                                 : "=v"(w2) : "a"(wa[4*c+2]));                 \
                    asm volatile("v_accvgpr_read_b32 %0, %1"                   \
                                 : "=v"(w3) : "a"(wa[4*c+3]));                 \
                } else {                                                       \
                    float4 wl = wlds[c - 21][t];                               \
                    w0 = wl.x; w1 = wl.y; w2 = wl.z; w3 = wl.w;                \
                }                                                              \
                a0 += w0*sA0 + w1*sA1 + w2*sA2 + w3*sA3;                       \
                a1 += w0*sB0 + w1*sB1 + w2*sB2 + w3*sB3;                       \
                if (DO_X) {                                                    \
                    const float4 w4 = xw[c * nact];                            \
                    xa0 += w4.x*sA0 + w4.y*sA1 + w4.z*sA2 + w4.w*sA3;          \
                    xa1 += w4.x*sB0 + w4.y*sB1 + w4.z*sB2 + w4.w*sB3;          \
                }                                                              \
                __builtin_amdgcn_sched_barrier(0);                             \
            }

            if (xtr) { PHASE_A_LOOP(true) } else { PHASE_A_LOOP(false) }
#undef PHASE_A_LOOP

            gAll[0][t] = a0; gAll[1][t] = a1;
            if (xtr && lane < nact) { gX[0][xu0 + lane] = xa0; gX[1][xu0 + lane] = xa1; }
        }
        if (ydtick && t < 200) {
            atomicAdd(&yacc[ub], sfcw[uj] * shs[1][ub][uj]);
        }
        __syncthreads();

        // ================= Phase B: cell updates =================
        if (t < 200) {
            if (tick < 8064) {               // L0, global step g0 = tick
                const int s = tick / LSEQ, p = tick % LSEQ;
                float x;
                if (s == 0)            x = xrow[p];
                else if (p < LSEQ - 1) x = xrow[p + 1];
                else                   x = ybuf[ub];
                const int j = uj, b = ub;
                float Gi = sb0[j]       + sw0[j]       * x + gAll[b][j];
                float Gf = sb0[100 + j] + sw0[100 + j] * x + gAll[b][100 + j];
                float Gg = sb0[200 + j] + sw0[200 + j] * x + gAll[b][200 + j];
                float Go = sb0[300 + j] + sw0[300 + j] * x + gAll[b][300 + j];
                c0 = sigmoidf_(Gf) * c0 + sigmoidf_(Gi) * tanhf_(Gg);
                shs[0][b][j] = sigmoidf_(Go) * tanhf_(c0);
            }
        } else if (t < 400) {
            if (tick >= 1 && tick <= 8064) { // L1, global step g1 = tick-1
                const int j = uj, b = ub;
                // Wih1 row r: r<368 -> gAll[b][400+r], else gX[b][144+(r-368)]
                // Whh1 row r: r<256 -> gAll[b][768+r], else gX[b][r-256]
                float Gi = sb1[j]       + gAll[b][400 + j] + gAll[b][768 + j];
                float Gf = sb1[100 + j] + gAll[b][500 + j] + gAll[b][868 + j];
                float Gg = sb1[200 + j] + gAll[b][600 + j]
                         + ((j < 56) ? gAll[b][968 + j] : gX[b][j - 56]);
                float Go = sb1[300 + j]
                         + ((j < 68) ? gAll[b][700 + j] : gX[b][144 + j - 68])
                         + gX[b][44 + j];
                c1 = sigmoidf_(Gf) * c1 + sigmoidf_(Gi) * tanhf_(Gg);
                shs[1][b][j] = sigmoidf_(Go) * tanhf_(c1);
            }
        } else if (t == 1023) {
            if (ydtick) {
                const int s = (tick - 2) / LSEQ;
                float y0 = yacc[0] + fcb0;
                float y1 = yacc[1] + fcb0;
                ybuf[0] = y0; ybuf[1] = y1;
                out[b0 * STEPS + s]       = y0;
                out[(b0 + 1) * STEPS + s] = y1;
                yacc[0] = 0.0f; yacc[1] = 0.0f;
            }
        }
        __syncthreads();
    }
}

extern "C" void kernel_launch(void* const* d_in, const int* in_sizes, int n_in,
                              void* d_out, int out_size, void* d_ws, size_t ws_size,
                              hipStream_t stream) {
    const float* X    = (const float*)d_in[0];
    const float* Wih0 = (const float*)d_in[1];
    const float* Whh0 = (const float*)d_in[2];
    const float* bih0 = (const float*)d_in[3];
    const float* bhh0 = (const float*)d_in[4];
    const float* Wih1 = (const float*)d_in[5];
    const float* Whh1 = (const float*)d_in[6];
    const float* bih1 = (const float*)d_in[7];
    const float* bhh1 = (const float*)d_in[8];
    const float* fcw  = (const float*)d_in[9];
    const float* fcb  = (const float*)d_in[10];
    float* out = (float*)d_out;
    float* wsT = (float*)d_ws;   // 4400 float4 = 70,400 B

    hipLaunchKernelGGL(prep_kernel, dim3((NX4 * 4 + 255) / 256), dim3(256), 0, stream,
                       Wih1, Whh1, wsT);
    hipLaunchKernelGGL(lstm_kernel, dim3(256), dim3(1024), 0, stream,
                       X, Wih0, Whh0, bih0, bhh0, Wih1, Whh1, bih1, bhh1,
                       fcw, fcb, wsT, out);
}

// Round 5
// 39769.440 us; speedup vs baseline: 3.5858x; 3.0197x over previous
//
#include <hip/hip_runtime.h>

#define HH    100
#define G4    400
#define LSEQ  168
#define STEPS 48
#define NTICK 8066     // L0 at tick t (t<8064), L1 at tick t-1
#define SHP   112      // padded h stride (zeros beyond 100)
#define NX    176      // extra rows: Wih1 368..399 (32) + Whh1 256..399 (144)
#define NX4   4400     // float4 units in the extra-row panel
#define NX4P  4416     // padded (waves 13..15 read up to idx 4415)

__device__ __forceinline__ float sigmoidf_(float x) {
    return 1.0f / (1.0f + __expf(-x));
}
__device__ __forceinline__ float tanhf_(float x) {
    return 1.0f - 2.0f / (__expf(2.0f * x) + 1.0f);
}

// One weight-chunk of the dot product, fully encapsulated:
// 8 v_readlane (imm lane) + 8 v_fmac (SGPR src0). Readlane results live only
// inside the block ("=&s" temps); blocks chain through "+v" accumulators, so
// the scheduler cannot cluster readlanes across chunks (the rounds-1..4
// failure mode: 200 free-floating SGPR values -> spill cascade / serialization).
#define KCHUNK(c_, hvx, hvy, hvz, hvw, w0_, w1_, w2_, w3_)                     \
    asm("v_readlane_b32 %2, %4, %12\n\t"                                       \
        "v_readlane_b32 %3, %4, %13\n\t"                                       \
        "v_fmac_f32 %0, %2, %8\n\t"                                            \
        "v_fmac_f32 %1, %3, %8\n\t"                                            \
        "v_readlane_b32 %2, %5, %12\n\t"                                       \
        "v_readlane_b32 %3, %5, %13\n\t"                                       \
        "v_fmac_f32 %0, %2, %9\n\t"                                            \
        "v_fmac_f32 %1, %3, %9\n\t"                                            \
        "v_readlane_b32 %2, %6, %12\n\t"                                       \
        "v_readlane_b32 %3, %6, %13\n\t"                                       \
        "v_fmac_f32 %0, %2, %10\n\t"                                           \
        "v_fmac_f32 %1, %3, %10\n\t"                                           \
        "v_readlane_b32 %2, %7, %12\n\t"                                       \
        "v_readlane_b32 %3, %7, %13\n\t"                                       \
        "v_fmac_f32 %0, %2, %11\n\t"                                           \
        "v_fmac_f32 %1, %3, %11\n\t"                                           \
        : "+v"(a0), "+v"(a1), "=&s"(sA), "=&s"(sB)                             \
        : "v"(hvx), "v"(hvy), "v"(hvz), "v"(hvw),                              \
          "v"(w0_), "v"(w1_), "v"(w2_), "v"(w3_),                              \
          "n"(c_), "n"(28 + (c_)))

// Same, plus the extra-row stream FMAs (xa0/xa1 vs xw float4).
#define KCHUNK_X(c_, hvx, hvy, hvz, hvw, w0_, w1_, w2_, w3_, x0_, x1_, x2_, x3_)\
    asm("v_readlane_b32 %4, %6, %18\n\t"                                       \
        "v_readlane_b32 %5, %6, %19\n\t"                                       \
        "v_fmac_f32 %0, %4, %10\n\t"                                           \
        "v_fmac_f32 %1, %5, %10\n\t"                                           \
        "v_fmac_f32 %2, %4, %14\n\t"                                           \
        "v_fmac_f32 %3, %5, %14\n\t"                                           \
        "v_readlane_b32 %4, %7, %18\n\t"                                       \
        "v_readlane_b32 %5, %7, %19\n\t"                                       \
        "v_fmac_f32 %0, %4, %11\n\t"                                           \
        "v_fmac_f32 %1, %5, %11\n\t"                                           \
        "v_fmac_f32 %2, %4, %15\n\t"                                           \
        "v_fmac_f32 %3, %5, %15\n\t"                                           \
        "v_readlane_b32 %4, %8, %18\n\t"                                       \
        "v_readlane_b32 %5, %8, %19\n\t"                                       \
        "v_fmac_f32 %0, %4, %12\n\t"                                           \
        "v_fmac_f32 %1, %5, %12\n\t"                                           \
        "v_fmac_f32 %2, %4, %16\n\t"                                           \
        "v_fmac_f32 %3, %5, %16\n\t"                                           \
        "v_readlane_b32 %4, %9, %18\n\t"                                       \
        "v_readlane_b32 %5, %9, %19\n\t"                                       \
        "v_fmac_f32 %0, %4, %13\n\t"                                           \
        "v_fmac_f32 %1, %5, %13\n\t"                                           \
        "v_fmac_f32 %2, %4, %17\n\t"                                           \
        "v_fmac_f32 %3, %5, %17\n\t"                                           \
        : "+v"(a0), "+v"(a1), "+v"(xa0), "+v"(xa1), "=&s"(sA), "=&s"(sB)       \
        : "v"(hvx), "v"(hvy), "v"(hvz), "v"(hvw),                              \
          "v"(w0_), "v"(w1_), "v"(w2_), "v"(w3_),                              \
          "v"(x0_), "v"(x1_), "v"(x2_), "v"(x3_),                              \
          "n"(c_), "n"(28 + (c_)))

// Extra-row weights packed transposed for coalesced dwordx4 access.
// float4 units:
//   group 0 (wave 4, B-extras):  idx4 = c*32 + l           row = 368+l (l<32), src Wih1
//   group g=1..3 (waves 13..15): idx4 = 800 + (g-1)*1200 + c*48 + l
//                                row = 256 + (g-1)*48 + l (l<48), src Whh1
// c = 0..24 chunks of 4 (covers k=0..99 exactly). Total 4400 float4 = 70,400 B.
__global__ void prep_kernel(const float* __restrict__ Wih1,
                            const float* __restrict__ Whh1,
                            float* __restrict__ wsT) {
    int idx = blockIdx.x * 256 + threadIdx.x;     // float index
    if (idx >= NX4 * 4) return;
    int f = idx & 3, q4 = idx >> 2;
    float v;
    if (q4 < 800) {
        int c = q4 / 32, l = q4 % 32;
        v = Wih1[(368 + l) * HH + c * 4 + f];
    } else {
        int r = q4 - 800, grp = r / 1200, rr = r % 1200;
        int c = rr / 48, l = rr % 48;
        v = Whh1[(256 + grp * 48 + l) * HH + c * 4 + f];
    }
    wsT[idx] = v;
}

// 1024 threads = 16 waves = 4 waves/SIMD -> HARD 128-reg cap (arch+acc,
// gfx950 unified file; reported VGPR_Count=64 is arch-only).
// Wave-aligned unit map (thread t owns one K=100 row-unit):
//   t <  400 : Whh0 row t        (input h0)  -> L0 gate partial, gAll[b][t]
//   t <  768 : Wih1 row t-400    (input h0)  -> L1 "a" partial,  gAll[b][400+r]
//   t < 1024 : Whh1 row t-768    (input h1)  -> L1 "b" partial,  gAll[b][768+r]
// Extra rows staged in LDS (xlds), one heavy wave per SIMD:
//   wave  4 : Wih1 rows 368..399 (h0) -> gX[b][144+l]
//   wave 13 : Whh1 rows 256..303 (h1) -> gX[b][l]
//   wave 14 : Whh1 rows 304..351 (h1) -> gX[b][48+l]
//   wave 15 : Whh1 rows 352..399 (h1) -> gX[b][96+l]
// h distribution: ONE ds_read_b128/wave (lane c holds h-chunk c for both
// batches of the wave's input layer), then in-asm v_readlane -> SGPR -> fmac.
__global__
__attribute__((amdgpu_flat_work_group_size(1024, 1024), amdgpu_waves_per_eu(4, 4)))
void lstm_kernel(const float* __restrict__ X,     // (512,168)
                 const float* __restrict__ Wih0,  // (400,1)
                 const float* __restrict__ Whh0,  // (400,100)
                 const float* __restrict__ bih0,
                 const float* __restrict__ bhh0,
                 const float* __restrict__ Wih1,  // (400,100)
                 const float* __restrict__ Whh1,  // (400,100)
                 const float* __restrict__ bih1,
                 const float* __restrict__ bhh1,
                 const float* __restrict__ fcw,   // (100)
                 const float* __restrict__ fcb,   // (1)
                 const float* __restrict__ wsT,   // extra rows, packed
                 float* __restrict__ out)         // (512,48)
{
    __shared__ __align__(16) float shs[2][2][SHP];   // [layer][batch][k], pad zeros
    __shared__ __align__(16) float4 wlds[2][1024];   // weight chunks 23,24 per unit
    __shared__ __align__(16) float4 xlds[NX4P];      // extra-row panel (70.6 KB)
    __shared__ float gAll[2][1024];                  // per-batch unit partials
    __shared__ float gX[2][NX];                      // extra-row full-dot partials
    __shared__ float sb0[G4], sb1[G4], sw0[G4], sfcw[HH];
    __shared__ float yacc[2], ybuf[2];

    const int t    = threadIdx.x;
    const int lane = t & 63;
    const int wid  = t >> 6;
    const int wg   = blockIdx.x;
    const int b0   = wg * 2;

    // ---- one-time init ----
    for (int i = t; i < 2 * 2 * SHP; i += 1024) ((float*)shs)[i] = 0.0f;
    for (int i = t; i < NX4P; i += 1024)
        xlds[i] = (i < NX4) ? ((const float4*)wsT)[i] : make_float4(0.f, 0.f, 0.f, 0.f);
    if (t < G4) {
        sb0[t] = bih0[t] + bhh0[t];
        sb1[t] = bih1[t] + bhh1[t];
        sw0[t] = Wih0[t];
    }
    if (t < HH) sfcw[t] = fcw[t];
    if (t == 0) { yacc[0] = yacc[1] = 0.0f; ybuf[0] = ybuf[1] = 0.0f; }
    const float fcb0 = fcb[0];

    // ---- register-resident weights: 92 floats (23 float4 chunks) ----
    // Round-0-proven pin: allocator splits ~64 arch + ~28 acc itself.
    const float* wrow = (t < 400) ? (Whh0 + t * HH)
                      : (t < 768) ? (Wih1 + (t - 400) * HH)
                                  : (Whh1 + (t - 768) * HH);
    float wv[92];
    #pragma unroll
    for (int j = 0; j < 23; ++j) {
        float4 a = ((const float4*)wrow)[j];
        wv[4*j] = a.x; wv[4*j+1] = a.y; wv[4*j+2] = a.z; wv[4*j+3] = a.w;
    }
    #pragma unroll
    for (int j = 0; j < 92; j += 4)
        asm volatile("" : "+v"(wv[j]), "+v"(wv[j+1]), "+v"(wv[j+2]), "+v"(wv[j+3]));
    // chunks 23,24 live in LDS
    wlds[0][t] = ((const float4*)wrow)[23];
    wlds[1][t] = ((const float4*)wrow)[24];

    // wave-uniform input layer for the main FMA (h0 for waves 0..11, h1 for 12..15)
    const float* hbase = (t < 768) ? &shs[0][0][0] : &shs[1][0][0];

    // extra-row stream config (wave-uniform)
    const bool xtr   = (wid == 4) || (wid >= 13);
    const int  nact  = (wid == 4) ? 32 : 48;
    const int  xbase = (wid == 4) ? 0 : 800 + (wid - 13) * 1200;
    const int  xu0   = (wid == 4) ? 144 : (wid - 13) * 48;
    const float4* xw = xlds + xbase + lane;          // + c*nact per chunk (LDS)

    // cell-update params
    float c0 = 0.0f, c1 = 0.0f;
    const int ub = (t < 200) ? (t / 100) : ((t - 200) / 100);
    const int uj = (t < 200) ? (t % 100) : ((t - 200) % 100);
    const float* xrow = X + (b0 + ub) * LSEQ;

    __syncthreads();

    #pragma unroll 1
    for (int tick = 0; tick < NTICK; ++tick) {
        const bool ydtick = (tick >= 2) && ((tick - 2) % LSEQ == LSEQ - 1);

        // ================= Phase A: all FMA work =================
        {
            // lane c holds h chunk c: batch A = chunks 0..24, batch B = 28..52
            const int li = (lane < 56) ? lane : 55;
            const float4 hv = ((const float4*)hbase)[li];   // ONE ds_read_b128
            float a0 = 0.f, a1 = 0.f, xa0 = 0.f, xa1 = 0.f;
            float sA, sB;

            if (!xtr) {
                #pragma unroll
                for (int c = 0; c < 25; ++c) {
                    if (c < 23) {
                        KCHUNK(c, hv.x, hv.y, hv.z, hv.w,
                               wv[4*c], wv[4*c+1], wv[4*c+2], wv[4*c+3]);
                    } else {
                        float4 wl = wlds[c - 23][t];
                        KCHUNK(c, hv.x, hv.y, hv.z, hv.w, wl.x, wl.y, wl.z, wl.w);
                    }
                }
            } else {
                #pragma unroll
                for (int c = 0; c < 25; ++c) {
                    const float4 w4 = xw[c * nact];
                    if (c < 23) {
                        KCHUNK_X(c, hv.x, hv.y, hv.z, hv.w,
                                 wv[4*c], wv[4*c+1], wv[4*c+2], wv[4*c+3],
                                 w4.x, w4.y, w4.z, w4.w);
                    } else {
                        float4 wl = wlds[c - 23][t];
                        KCHUNK_X(c, hv.x, hv.y, hv.z, hv.w,
                                 wl.x, wl.y, wl.z, wl.w,
                                 w4.x, w4.y, w4.z, w4.w);
                    }
                }
            }

            gAll[0][t] = a0; gAll[1][t] = a1;
            if (xtr && lane < nact) { gX[0][xu0 + lane] = xa0; gX[1][xu0 + lane] = xa1; }
        }
        if (ydtick && t < 200) {
            atomicAdd(&yacc[ub], sfcw[uj] * shs[1][ub][uj]);
        }
        __syncthreads();

        // ================= Phase B: cell updates =================
        if (t < 200) {
            if (tick < 8064) {               // L0, global step g0 = tick
                const int s = tick / LSEQ, p = tick % LSEQ;
                float x;
                if (s == 0)            x = xrow[p];
                else if (p < LSEQ - 1) x = xrow[p + 1];
                else                   x = ybuf[ub];
                const int j = uj, b = ub;
                float Gi = sb0[j]       + sw0[j]       * x + gAll[b][j];
                float Gf = sb0[100 + j] + sw0[100 + j] * x + gAll[b][100 + j];
                float Gg = sb0[200 + j] + sw0[200 + j] * x + gAll[b][200 + j];
                float Go = sb0[300 + j] + sw0[300 + j] * x + gAll[b][300 + j];
                c0 = sigmoidf_(Gf) * c0 + sigmoidf_(Gi) * tanhf_(Gg);
                shs[0][b][j] = sigmoidf_(Go) * tanhf_(c0);
            }
        } else if (t < 400) {
            if (tick >= 1 && tick <= 8064) { // L1, global step g1 = tick-1
                const int j = uj, b = ub;
                // Wih1 row r: r<368 -> gAll[b][400+r], else gX[b][144+(r-368)]
                // Whh1 row r: r<256 -> gAll[b][768+r], else gX[b][r-256]
                float Gi = sb1[j]       + gAll[b][400 + j] + gAll[b][768 + j];
                float Gf = sb1[100 + j] + gAll[b][500 + j] + gAll[b][868 + j];
                float Gg = sb1[200 + j] + gAll[b][600 + j]
                         + ((j < 56) ? gAll[b][968 + j] : gX[b][j - 56]);
                float Go = sb1[300 + j]
                         + ((j < 68) ? gAll[b][700 + j] : gX[b][144 + j - 68])
                         + gX[b][44 + j];
                c1 = sigmoidf_(Gf) * c1 + sigmoidf_(Gi) * tanhf_(Gg);
                shs[1][b][j] = sigmoidf_(Go) * tanhf_(c1);
            }
        } else if (t == 1023) {
            if (ydtick) {
                const int s = (tick - 2) / LSEQ;
                float y0 = yacc[0] + fcb0;
                float y1 = yacc[1] + fcb0;
                ybuf[0] = y0; ybuf[1] = y1;
                out[b0 * STEPS + s]       = y0;
                out[(b0 + 1) * STEPS + s] = y1;
                yacc[0] = 0.0f; yacc[1] = 0.0f;
            }
        }
        __syncthreads();
    }
}

extern "C" void kernel_launch(void* const* d_in, const int* in_sizes, int n_in,
                              void* d_out, int out_size, void* d_ws, size_t ws_size,
                              hipStream_t stream) {
    const float* X    = (const float*)d_in[0];
    const float* Wih0 = (const float*)d_in[1];
    const float* Whh0 = (const float*)d_in[2];
    const float* bih0 = (const float*)d_in[3];
    const float* bhh0 = (const float*)d_in[4];
    const float* Wih1 = (const float*)d_in[5];
    const float* Whh1 = (const float*)d_in[6];
    const float* bih1 = (const float*)d_in[7];
    const float* bhh1 = (const float*)d_in[8];
    const float* fcw  = (const float*)d_in[9];
    const float* fcb  = (const float*)d_in[10];
    float* out = (float*)d_out;
    float* wsT = (float*)d_ws;   // 4400 float4 = 70,400 B

    hipLaunchKernelGGL(prep_kernel, dim3((NX4 * 4 + 255) / 256), dim3(256), 0, stream,
                       Wih1, Whh1, wsT);
    hipLaunchKernelGGL(lstm_kernel, dim3(256), dim3(1024), 0, stream,
                       X, Wih0, Whh0, bih0, bhh0, Wih1, Whh1, bih1, bhh1,
                       fcw, fcb, wsT, out);
}

// Round 6
// 39167.545 us; speedup vs baseline: 3.6409x; 1.0154x over previous
//
#include <hip/hip_runtime.h>

#define HH    100
#define G4    400
#define LSEQ  168
#define STEPS 48
#define NTICK 8066     // L0 at tick t (t<8064), L1 at tick t-1
#define SHP   112      // padded h stride (zeros beyond 100)
#define NX    176      // extra rows: Wih1 368..399 (32) + Whh1 256..399 (144)
#define NX4   4400     // float4 units in the extra-row panel
#define NX4P  4416     // padded (waves 13..15 read up to idx 4415)

__device__ __forceinline__ float sigmoidf_(float x) {
    return 1.0f / (1.0f + __expf(-x));
}
__device__ __forceinline__ float tanhf_(float x) {
    return 1.0f - 2.0f / (__expf(2.0f * x) + 1.0f);
}

// One weight-chunk of the dot product, fully encapsulated.
// Round-5 lesson: RL->fmac distance of 2 instrs stalls on the
// VALU-writes-SGPR -> VALU-reads-SGPR hazard (~2-4 cy per fmac = ~8k
// stall cycles/tick). Fix: 8 readlanes FIRST (8 distinct SGPR temps),
// then the fmacs -- every RL->consumer distance >= 8 instrs (16 cy).
// Blocks stay indivisible and chain through "+v" accumulators, so the
// rounds-1..4 readlane-clustering/spill cascade cannot return.
#define KCHUNK(c_, hvx, hvy, hvz, hvw, w0_, w1_, w2_, w3_)                     \
    asm("v_readlane_b32 %2, %10, %18\n\t"                                      \
        "v_readlane_b32 %3, %10, %19\n\t"                                      \
        "v_readlane_b32 %4, %11, %18\n\t"                                      \
        "v_readlane_b32 %5, %11, %19\n\t"                                      \
        "v_readlane_b32 %6, %12, %18\n\t"                                      \
        "v_readlane_b32 %7, %12, %19\n\t"                                      \
        "v_readlane_b32 %8, %13, %18\n\t"                                      \
        "v_readlane_b32 %9, %13, %19\n\t"                                      \
        "v_fmac_f32 %0, %2, %14\n\t"                                           \
        "v_fmac_f32 %1, %3, %14\n\t"                                           \
        "v_fmac_f32 %0, %4, %15\n\t"                                           \
        "v_fmac_f32 %1, %5, %15\n\t"                                           \
        "v_fmac_f32 %0, %6, %16\n\t"                                           \
        "v_fmac_f32 %1, %7, %16\n\t"                                           \
        "v_fmac_f32 %0, %8, %17\n\t"                                           \
        "v_fmac_f32 %1, %9, %17\n\t"                                           \
        : "+v"(a0), "+v"(a1),                                                  \
          "=&s"(s0), "=&s"(s1), "=&s"(s2), "=&s"(s3),                          \
          "=&s"(s4), "=&s"(s5), "=&s"(s6), "=&s"(s7)                           \
        : "v"(hvx), "v"(hvy), "v"(hvz), "v"(hvw),                              \
          "v"(w0_), "v"(w1_), "v"(w2_), "v"(w3_),                              \
          "n"(c_), "n"(28 + (c_)))

// Same, plus the extra-row stream FMAs (xa0/xa1 vs xw float4).
// fmac order interleaves the four accumulator chains -> each chain's
// ops are >= 4 instrs (8 cy) apart, covering FMA latency.
#define KCHUNK_X(c_, hvx, hvy, hvz, hvw, w0_, w1_, w2_, w3_, x0_, x1_, x2_, x3_)\
    asm("v_readlane_b32 %4, %12, %24\n\t"                                      \
        "v_readlane_b32 %5, %12, %25\n\t"                                      \
        "v_readlane_b32 %6, %13, %24\n\t"                                      \
        "v_readlane_b32 %7, %13, %25\n\t"                                      \
        "v_readlane_b32 %8, %14, %24\n\t"                                      \
        "v_readlane_b32 %9, %14, %25\n\t"                                      \
        "v_readlane_b32 %10, %15, %24\n\t"                                     \
        "v_readlane_b32 %11, %15, %25\n\t"                                     \
        "v_fmac_f32 %0, %4, %16\n\t"                                           \
        "v_fmac_f32 %1, %5, %16\n\t"                                           \
        "v_fmac_f32 %2, %4, %20\n\t"                                           \
        "v_fmac_f32 %3, %5, %20\n\t"                                           \
        "v_fmac_f32 %0, %6, %17\n\t"                                           \
        "v_fmac_f32 %1, %7, %17\n\t"                                           \
        "v_fmac_f32 %2, %6, %21\n\t"                                           \
        "v_fmac_f32 %3, %7, %21\n\t"                                           \
        "v_fmac_f32 %0, %8, %18\n\t"                                           \
        "v_fmac_f32 %1, %9, %18\n\t"                                           \
        "v_fmac_f32 %2, %8, %22\n\t"                                           \
        "v_fmac_f32 %3, %9, %22\n\t"                                           \
        "v_fmac_f32 %0, %10, %19\n\t"                                          \
        "v_fmac_f32 %1, %11, %19\n\t"                                          \
        "v_fmac_f32 %2, %10, %23\n\t"                                          \
        "v_fmac_f32 %3, %11, %23\n\t"                                          \
        : "+v"(a0), "+v"(a1), "+v"(xa0), "+v"(xa1),                            \
          "=&s"(s0), "=&s"(s1), "=&s"(s2), "=&s"(s3),                          \
          "=&s"(s4), "=&s"(s5), "=&s"(s6), "=&s"(s7)                           \
        : "v"(hvx), "v"(hvy), "v"(hvz), "v"(hvw),                              \
          "v"(w0_), "v"(w1_), "v"(w2_), "v"(w3_),                              \
          "v"(x0_), "v"(x1_), "v"(x2_), "v"(x3_),                              \
          "n"(c_), "n"(28 + (c_)))

// Extra-row weights packed transposed for coalesced dwordx4 access.
// float4 units:
//   group 0 (wave 4, B-extras):  idx4 = c*32 + l           row = 368+l (l<32), src Wih1
//   group g=1..3 (waves 13..15): idx4 = 800 + (g-1)*1200 + c*48 + l
//                                row = 256 + (g-1)*48 + l (l<48), src Whh1
// c = 0..24 chunks of 4 (covers k=0..99 exactly). Total 4400 float4 = 70,400 B.
__global__ void prep_kernel(const float* __restrict__ Wih1,
                            const float* __restrict__ Whh1,
                            float* __restrict__ wsT) {
    int idx = blockIdx.x * 256 + threadIdx.x;     // float index
    if (idx >= NX4 * 4) return;
    int f = idx & 3, q4 = idx >> 2;
    float v;
    if (q4 < 800) {
        int c = q4 / 32, l = q4 % 32;
        v = Wih1[(368 + l) * HH + c * 4 + f];
    } else {
        int r = q4 - 800, grp = r / 1200, rr = r % 1200;
        int c = rr / 48, l = rr % 48;
        v = Whh1[(256 + grp * 48 + l) * HH + c * 4 + f];
    }
    wsT[idx] = v;
}

// 1024 threads = 16 waves = 4 waves/SIMD -> HARD 128-reg cap (arch+acc,
// gfx950 unified file; reported VGPR_Count=64 is arch-only).
// Wave-aligned unit map (thread t owns one K=100 row-unit):
//   t <  400 : Whh0 row t        (input h0)  -> L0 gate partial, gAll[b][t]
//   t <  768 : Wih1 row t-400    (input h0)  -> L1 "a" partial,  gAll[b][400+r]
//   t < 1024 : Whh1 row t-768    (input h1)  -> L1 "b" partial,  gAll[b][768+r]
// Extra rows staged in LDS (xlds), one heavy wave per SIMD:
//   wave  4 : Wih1 rows 368..399 (h0) -> gX[b][144+l]
//   wave 13 : Whh1 rows 256..303 (h1) -> gX[b][l]
//   wave 14 : Whh1 rows 304..351 (h1) -> gX[b][48+l]
//   wave 15 : Whh1 rows 352..399 (h1) -> gX[b][96+l]
// h distribution: ONE ds_read_b128/wave (lane c holds h-chunk c for both
// batches of the wave's input layer), then in-asm v_readlane -> SGPR -> fmac.
__global__
__attribute__((amdgpu_flat_work_group_size(1024, 1024), amdgpu_waves_per_eu(4, 4)))
void lstm_kernel(const float* __restrict__ X,     // (512,168)
                 const float* __restrict__ Wih0,  // (400,1)
                 const float* __restrict__ Whh0,  // (400,100)
                 const float* __restrict__ bih0,
                 const float* __restrict__ bhh0,
                 const float* __restrict__ Wih1,  // (400,100)
                 const float* __restrict__ Whh1,  // (400,100)
                 const float* __restrict__ bih1,
                 const float* __restrict__ bhh1,
                 const float* __restrict__ fcw,   // (100)
                 const float* __restrict__ fcb,   // (1)
                 const float* __restrict__ wsT,   // extra rows, packed
                 float* __restrict__ out)         // (512,48)
{
    __shared__ __align__(16) float shs[2][2][SHP];   // [layer][batch][k], pad zeros
    __shared__ __align__(16) float4 wlds[2][1024];   // weight chunks 23,24 per unit
    __shared__ __align__(16) float4 xlds[NX4P];      // extra-row panel (70.6 KB)
    __shared__ float gAll[2][1024];                  // per-batch unit partials
    __shared__ float gX[2][NX];                      // extra-row full-dot partials
    __shared__ float sb0[G4], sb1[G4], sw0[G4], sfcw[HH];
    __shared__ float yacc[2], ybuf[2];

    const int t    = threadIdx.x;
    const int lane = t & 63;
    const int wid  = t >> 6;
    const int wg   = blockIdx.x;
    const int b0   = wg * 2;

    // ---- one-time init ----
    for (int i = t; i < 2 * 2 * SHP; i += 1024) ((float*)shs)[i] = 0.0f;
    for (int i = t; i < NX4P; i += 1024)
        xlds[i] = (i < NX4) ? ((const float4*)wsT)[i] : make_float4(0.f, 0.f, 0.f, 0.f);
    if (t < G4) {
        sb0[t] = bih0[t] + bhh0[t];
        sb1[t] = bih1[t] + bhh1[t];
        sw0[t] = Wih0[t];
    }
    if (t < HH) sfcw[t] = fcw[t];
    if (t == 0) { yacc[0] = yacc[1] = 0.0f; ybuf[0] = ybuf[1] = 0.0f; }
    const float fcb0 = fcb[0];

    // ---- register-resident weights: 92 floats (23 float4 chunks) ----
    // Round-0-proven pin: allocator splits ~64 arch + ~28 acc itself.
    const float* wrow = (t < 400) ? (Whh0 + t * HH)
                      : (t < 768) ? (Wih1 + (t - 400) * HH)
                                  : (Whh1 + (t - 768) * HH);
    float wv[92];
    #pragma unroll
    for (int j = 0; j < 23; ++j) {
        float4 a = ((const float4*)wrow)[j];
        wv[4*j] = a.x; wv[4*j+1] = a.y; wv[4*j+2] = a.z; wv[4*j+3] = a.w;
    }
    #pragma unroll
    for (int j = 0; j < 92; j += 4)
        asm volatile("" : "+v"(wv[j]), "+v"(wv[j+1]), "+v"(wv[j+2]), "+v"(wv[j+3]));
    // chunks 23,24 live in LDS
    wlds[0][t] = ((const float4*)wrow)[23];
    wlds[1][t] = ((const float4*)wrow)[24];

    // wave-uniform input layer for the main FMA (h0 for waves 0..11, h1 for 12..15)
    const float* hbase = (t < 768) ? &shs[0][0][0] : &shs[1][0][0];

    // extra-row stream config (wave-uniform)
    const bool xtr   = (wid == 4) || (wid >= 13);
    const int  nact  = (wid == 4) ? 32 : 48;
    const int  xbase = (wid == 4) ? 0 : 800 + (wid - 13) * 1200;
    const int  xu0   = (wid == 4) ? 144 : (wid - 13) * 48;
    const float4* xw = xlds + xbase + lane;          // + c*nact per chunk (LDS)

    // cell-update params
    float c0 = 0.0f, c1 = 0.0f;
    const int ub = (t < 200) ? (t / 100) : ((t - 200) / 100);
    const int uj = (t < 200) ? (t % 100) : ((t - 200) % 100);
    const float* xrow = X + (b0 + ub) * LSEQ;

    __syncthreads();

    #pragma unroll 1
    for (int tick = 0; tick < NTICK; ++tick) {
        const bool ydtick = (tick >= 2) && ((tick - 2) % LSEQ == LSEQ - 1);

        // ================= Phase A: all FMA work =================
        {
            // lane c holds h chunk c: batch A = chunks 0..24, batch B = 28..52
            const int li = (lane < 56) ? lane : 55;
            const float4 hv = ((const float4*)hbase)[li];   // ONE ds_read_b128
            float a0 = 0.f, a1 = 0.f, xa0 = 0.f, xa1 = 0.f;
            float s0, s1, s2, s3, s4, s5, s6, s7;

            if (!xtr) {
                #pragma unroll
                for (int c = 0; c < 25; ++c) {
                    if (c < 23) {
                        KCHUNK(c, hv.x, hv.y, hv.z, hv.w,
                               wv[4*c], wv[4*c+1], wv[4*c+2], wv[4*c+3]);
                    } else {
                        float4 wl = wlds[c - 23][t];
                        KCHUNK(c, hv.x, hv.y, hv.z, hv.w, wl.x, wl.y, wl.z, wl.w);
                    }
                }
            } else {
                #pragma unroll
                for (int c = 0; c < 25; ++c) {
                    const float4 w4 = xw[c * nact];
                    if (c < 23) {
                        KCHUNK_X(c, hv.x, hv.y, hv.z, hv.w,
                                 wv[4*c], wv[4*c+1], wv[4*c+2], wv[4*c+3],
                                 w4.x, w4.y, w4.z, w4.w);
                    } else {
                        float4 wl = wlds[c - 23][t];
                        KCHUNK_X(c, hv.x, hv.y, hv.z, hv.w,
                                 wl.x, wl.y, wl.z, wl.w,
                                 w4.x, w4.y, w4.z, w4.w);
                    }
                }
            }

            gAll[0][t] = a0; gAll[1][t] = a1;
            if (xtr && lane < nact) { gX[0][xu0 + lane] = xa0; gX[1][xu0 + lane] = xa1; }
        }
        if (ydtick && t < 200) {
            atomicAdd(&yacc[ub], sfcw[uj] * shs[1][ub][uj]);
        }
        __syncthreads();

        // ================= Phase B: cell updates =================
        if (t < 200) {
            if (tick < 8064) {               // L0, global step g0 = tick
                const int s = tick / LSEQ, p = tick % LSEQ;
                float x;
                if (s == 0)            x = xrow[p];
                else if (p < LSEQ - 1) x = xrow[p + 1];
                else                   x = ybuf[ub];
                const int j = uj, b = ub;
                float Gi = sb0[j]       + sw0[j]       * x + gAll[b][j];
                float Gf = sb0[100 + j] + sw0[100 + j] * x + gAll[b][100 + j];
                float Gg = sb0[200 + j] + sw0[200 + j] * x + gAll[b][200 + j];
                float Go = sb0[300 + j] + sw0[300 + j] * x + gAll[b][300 + j];
                c0 = sigmoidf_(Gf) * c0 + sigmoidf_(Gi) * tanhf_(Gg);
                shs[0][b][j] = sigmoidf_(Go) * tanhf_(c0);
            }
        } else if (t < 400) {
            if (tick >= 1 && tick <= 8064) { // L1, global step g1 = tick-1
                const int j = uj, b = ub;
                // Wih1 row r: r<368 -> gAll[b][400+r], else gX[b][144+(r-368)]
                // Whh1 row r: r<256 -> gAll[b][768+r], else gX[b][r-256]
                float Gi = sb1[j]       + gAll[b][400 + j] + gAll[b][768 + j];
                float Gf = sb1[100 + j] + gAll[b][500 + j] + gAll[b][868 + j];
                float Gg = sb1[200 + j] + gAll[b][600 + j]
                         + ((j < 56) ? gAll[b][968 + j] : gX[b][j - 56]);
                float Go = sb1[300 + j]
                         + ((j < 68) ? gAll[b][700 + j] : gX[b][144 + j - 68])
                         + gX[b][44 + j];
                c1 = sigmoidf_(Gf) * c1 + sigmoidf_(Gi) * tanhf_(Gg);
                shs[1][b][j] = sigmoidf_(Go) * tanhf_(c1);
            }
        } else if (t == 1023) {
            if (ydtick) {
                const int s = (tick - 2) / LSEQ;
                float y0 = yacc[0] + fcb0;
                float y1 = yacc[1] + fcb0;
                ybuf[0] = y0; ybuf[1] = y1;
                out[b0 * STEPS + s]       = y0;
                out[(b0 + 1) * STEPS + s] = y1;
                yacc[0] = 0.0f; yacc[1] = 0.0f;
            }
        }
        __syncthreads();
    }
}

extern "C" void kernel_launch(void* const* d_in, const int* in_sizes, int n_in,
                              void* d_out, int out_size, void* d_ws, size_t ws_size,
                              hipStream_t stream) {
    const float* X    = (const float*)d_in[0];
    const float* Wih0 = (const float*)d_in[1];
    const float* Whh0 = (const float*)d_in[2];
    const float* bih0 = (const float*)d_in[3];
    const float* bhh0 = (const float*)d_in[4];
    const float* Wih1 = (const float*)d_in[5];
    const float* Whh1 = (const float*)d_in[6];
    const float* bih1 = (const float*)d_in[7];
    const float* bhh1 = (const float*)d_in[8];
    const float* fcw  = (const float*)d_in[9];
    const float* fcb  = (const float*)d_in[10];
    float* out = (float*)d_out;
    float* wsT = (float*)d_ws;   // 4400 float4 = 70,400 B

    hipLaunchKernelGGL(prep_kernel, dim3((NX4 * 4 + 255) / 256), dim3(256), 0, stream,
                       Wih1, Whh1, wsT);
    hipLaunchKernelGGL(lstm_kernel, dim3(256), dim3(1024), 0, stream,
                       X, Wih0, Whh0, bih0, bhh0, Wih1, Whh1, bih1, bhh1,
                       fcw, fcb, wsT, out);
}